// Round 2
// baseline (2592.986 us; speedup 1.0000x reference)
//
#include <hip/hip_runtime.h>

// out[b, d] = sum_k sc[b,k] * dict[serp(d), k]
// B = 262144, K = 32, D = S*S = 900, S = 30.
// Serpentine: for output d = r*30 + c with odd r, source column is r*30 + (29-c).
//
// Mapping: lane = output column d (coalesced stores own the roofline: 944 MB
// written vs 34 MB read). Dict rows pinned in VGPRs (64 regs), sc row is
// block-uniform -> SGPRs via s_load. Latency hiding comes from residency:
// 6 blocks/CU (24 waves) x ~15% per-wave duty covers the ~900-cycle HBM
// latency of the serial per-iteration s-row load.

constexpr int KD    = 32;   // inner dim
constexpr int DDIM  = 900;  // S*S
constexpr int SDIM  = 30;
constexpr int BTILE = 32;   // b-rows per block (small: tail-balance across 10.7 rounds)

__device__ __forceinline__ int serp_src(int d) {
    int r = d / SDIM;
    int c = d - r * SDIM;
    return (r & 1) ? (r * SDIM + (SDIM - 1 - c)) : d;
}

// 6 blocks/CU: VGPR cap = 512/6 ~= 85, kernel uses ~72 -> fits without spill.
__global__ __launch_bounds__(256, 6) void serp_decode(
    const float* __restrict__ sc,     // [B, 32]
    const float* __restrict__ dict,   // [900, 32]
    float* __restrict__ out,          // [B, 900]
    int B)
{
    const int t  = threadIdx.x;
    const int d1 = blockIdx.x * 256 + t;   // 0..511 (grid.x == 2)
    const int d2 = d1 + 512;               // 512..1023
    const bool v2 = (d2 < DDIM);

    // Pin both dictionary rows (serpentine-remapped) in registers (L2-hot loads).
    float w1[KD], w2[KD];
    {
        const float4* p = reinterpret_cast<const float4*>(dict + (size_t)serp_src(d1) * KD);
        #pragma unroll
        for (int i = 0; i < KD / 4; ++i) {
            float4 v = p[i];
            w1[4*i+0] = v.x; w1[4*i+1] = v.y; w1[4*i+2] = v.z; w1[4*i+3] = v.w;
        }
        const int s2 = v2 ? serp_src(d2) : 0;   // safe in-bounds addr for masked lanes
        const float4* q = reinterpret_cast<const float4*>(dict + (size_t)s2 * KD);
        #pragma unroll
        for (int i = 0; i < KD / 4; ++i) {
            float4 v = q[i];
            w2[4*i+0] = v.x; w2[4*i+1] = v.y; w2[4*i+2] = v.z; w2[4*i+3] = v.w;
        }
    }

    const int b0 = blockIdx.y * BTILE;
    const float* __restrict__ srow = sc + (size_t)b0 * KD;   // block-uniform address
    float* __restrict__ o1 = out + (size_t)b0 * DDIM + d1;
    float* __restrict__ o2 = o1 + 512;

    const int nb = (B - b0 < BTILE) ? (B - b0) : BTILE;
    for (int bb = 0; bb < nb; ++bb) {
        // Sparse row: uniform address -> compiler emits scalar (SGPR) loads.
        float s[KD];
        #pragma unroll
        for (int i = 0; i < KD / 4; ++i) {
            float4 v = reinterpret_cast<const float4*>(srow)[i];
            s[4*i+0] = v.x; s[4*i+1] = v.y; s[4*i+2] = v.z; s[4*i+3] = v.w;
        }

        // 2 partial chains per output: dep-latency (4cyc) stays under issue rate.
        float a1a = 0.f, a1b = 0.f;
        #pragma unroll
        for (int i = 0; i < KD; i += 2) {
            a1a = fmaf(s[i],     w1[i],     a1a);
            a1b = fmaf(s[i + 1], w1[i + 1], a1b);
        }
        *o1 = a1a + a1b;

        if (v2) {   // whole-wave skip only for fully-inactive tail waves of block 1
            float a2a = 0.f, a2b = 0.f;
            #pragma unroll
            for (int i = 0; i < KD; i += 2) {
                a2a = fmaf(s[i],     w2[i],     a2a);
                a2b = fmaf(s[i + 1], w2[i + 1], a2b);
            }
            *o2 = a2a + a2b;
        }

        srow += KD;
        o1 += DDIM;
        o2 += DDIM;
    }
}

extern "C" void kernel_launch(void* const* d_in, const int* in_sizes, int n_in,
                              void* d_out, int out_size, void* d_ws, size_t ws_size,
                              hipStream_t stream) {
    const float* sc   = (const float*)d_in[0];   // [B, 32]
    const float* dict = (const float*)d_in[1];   // [900, 32]
    float* out        = (float*)d_out;           // [B, 1, 30, 30] flat = [B, 900]

    const int B = in_sizes[0] / KD;              // 262144

    dim3 grid(2, (unsigned)((B + BTILE - 1) / BTILE));
    serp_decode<<<grid, 256, 0, stream>>>(sc, dict, out, B);
}

// Round 3
// 1751.469 us; speedup vs baseline: 1.4805x; 1.4805x over previous
//
#include <hip/hip_runtime.h>

// out[b, d] = sum_k sc[b,k] * dict[serp(d), k]
// B = 262144, K = 32, D = S*S = 900, S = 30.
//
// R1 lesson: serial uniform HBM load of the sc row -> latency-bound (24% VALU).
// R2 lesson: launch_bounds(256,6) caps VGPR at 85 -> spills the 64-reg dict
//            pinning -> 9 GB scratch traffic. Keep regs, fix latency instead.
// R3: double-buffered LDS staging of sc tiles via global_load_lds (m97
// pattern). Loads for tile t+1 are in flight across the whole 64-row compute
// of tile t; the only vmcnt(0) drain is at the per-tile __syncthreads().

constexpr int KD    = 32;               // inner dim
constexpr int DDIM  = 900;              // S*S
constexpr int SDIM  = 30;
constexpr int TROWS = 64;               // sc rows staged per tile (8 KB)
constexpr int NT    = 4;                // tiles per block
constexpr int BROWS = TROWS * NT;       // 256 rows per block

__device__ __forceinline__ int serp_src(int d) {
    int r = d / SDIM;
    int c = d - r * SDIM;
    return (r & 1) ? (r * SDIM + (SDIM - 1 - c)) : d;
}

// 4 blocks/CU: VGPR cap = 128; kernel needs ~110 (w:64 + acc/sv/addr). No spill.
__global__ __launch_bounds__(256, 4) void serp_decode(
    const float* __restrict__ sc,     // [B, 32]
    const float* __restrict__ dict,   // [900, 32]
    float* __restrict__ out,          // [B, 900]
    int B)
{
    __shared__ float lds[2][TROWS * KD];   // 2 x 8 KB double buffer

    const int t    = threadIdx.x;
    const int lane = t & 63;
    const int wid  = t >> 6;               // wave id 0..3

    const int d1 = blockIdx.x * 256 + t;   // 0..511 (grid.x == 2)
    const int d2 = d1 + 512;               // 512..1023
    const bool v2 = (d2 < DDIM);

    // Pin both (serpentine-remapped) dictionary rows in 64 VGPRs.
    float w1[KD], w2[KD];
    {
        const float4* p = reinterpret_cast<const float4*>(dict + (size_t)serp_src(d1) * KD);
        #pragma unroll
        for (int i = 0; i < KD / 4; ++i) {
            float4 v = p[i];
            w1[4*i+0] = v.x; w1[4*i+1] = v.y; w1[4*i+2] = v.z; w1[4*i+3] = v.w;
        }
        const int s2 = v2 ? serp_src(d2) : 0;
        const float4* q = reinterpret_cast<const float4*>(dict + (size_t)s2 * KD);
        #pragma unroll
        for (int i = 0; i < KD / 4; ++i) {
            float4 v = q[i];
            w2[4*i+0] = v.x; w2[4*i+1] = v.y; w2[4*i+2] = v.z; w2[4*i+3] = v.w;
        }
    }

    const long long b0     = (long long)blockIdx.y * BROWS;
    const long long maxoff = (long long)B * KD - 4;   // safety clamp (B%BROWS==0 here)

    // Stage TROWS rows (8 KB) into lds[buf]: 8 chunks of 1 KB; wave `wid`
    // issues chunks {wid, wid+4}. LDS dest = wave-uniform chunk base (HW adds
    // lane*16); global src = per-lane address. Linear layouts match.
    auto stage = [&](int buf, int rbase) {
        #pragma unroll
        for (int c = 0; c < 2; ++c) {
            const int ch = wid + 4 * c;                         // chunk 0..7
            long long off = (b0 + rbase) * KD + ch * 256 + lane * 4;
            if (off > maxoff) off = maxoff;
            __builtin_amdgcn_global_load_lds(
                (const __attribute__((address_space(1))) void*)(sc + off),
                (__attribute__((address_space(3))) void*)(&lds[buf][ch * 256]),
                16, 0, 0);
        }
    };

    stage(0, 0);

    float* __restrict__ o1 = out + (size_t)b0 * DDIM + d1;
    int cur = 0;
    __syncthreads();                 // drains vmcnt(0): tile 0 resident

    for (int tile = 0; tile < NT; ++tile) {
        if (tile + 1 < NT) stage(cur ^ 1, (tile + 1) * TROWS);  // in flight all tile

        const float* S = lds[cur];
        #pragma unroll 4
        for (int bb = 0; bb < TROWS; ++bb) {
            const float4* srow = reinterpret_cast<const float4*>(S + bb * KD);
            float a1a = 0.f, a1b = 0.f, a2a = 0.f, a2b = 0.f;
            #pragma unroll
            for (int j = 0; j < KD / 4; ++j) {
                float4 sv = srow[j];               // uniform addr -> broadcast
                a1a = fmaf(sv.x, w1[4*j+0], a1a);
                a1b = fmaf(sv.y, w1[4*j+1], a1b);
                a1a = fmaf(sv.z, w1[4*j+2], a1a);
                a1b = fmaf(sv.w, w1[4*j+3], a1b);
                a2a = fmaf(sv.x, w2[4*j+0], a2a);
                a2b = fmaf(sv.y, w2[4*j+1], a2b);
                a2a = fmaf(sv.z, w2[4*j+2], a2a);
                a2b = fmaf(sv.w, w2[4*j+3], a2b);
            }
            o1[0] = a1a + a1b;                     // coalesced 256B/wave
            if (v2) o1[512] = a2a + a2b;
            o1 += DDIM;
        }
        __syncthreads();             // drains next tile's loads + this tile's reads
        cur ^= 1;
    }
}

extern "C" void kernel_launch(void* const* d_in, const int* in_sizes, int n_in,
                              void* d_out, int out_size, void* d_ws, size_t ws_size,
                              hipStream_t stream) {
    const float* sc   = (const float*)d_in[0];   // [B, 32]
    const float* dict = (const float*)d_in[1];   // [900, 32]
    float* out        = (float*)d_out;           // [B, 1, 30, 30] flat = [B, 900]

    const int B = in_sizes[0] / KD;              // 262144 (divisible by BROWS=256)

    dim3 grid(2, (unsigned)(B / BROWS));
    serp_decode<<<grid, 256, 0, stream>>>(sc, dict, out, B);
}

// Round 4
// 395.925 us; speedup vs baseline: 6.5492x; 4.4237x over previous
//
#include <hip/hip_runtime.h>

// out[b, d] = sum_k sc[b,k] * dict[serp(d), k]
// B = 262144, K = 32, D = S*S = 900, S = 30.
//
// R1: serial uniform SMEM load of sc row -> latency-bound (24% VALU, 643us).
// R2: launch_bounds(256,6) -> allocator squeezed to 40 VGPR, spilled dict regs
//     -> 9 GB scratch traffic (2593us).
// R3: launch_bounds(256,4) -> still squeezed (64 VGPR), 5.8 GB scratch (1751us).
//     Occupancy 33/68/47% for args 2/6/4 shows the 2nd arg pins the allocator's
//     occupancy TARGET and it spills to hit it.
// R4: SAME structure as R3 (async global_load_lds double-buffer, broadcast LDS
//     reads, 2 pinned dict rows/thread) but NO occupancy target (plain
//     __launch_bounds__(256): default policy does not spill for occupancy) and
//     unroll 4 -> 2 on the row loop to shrink live float4 ranges.

constexpr int KD    = 32;               // inner dim
constexpr int DDIM  = 900;              // S*S
constexpr int SDIM  = 30;
constexpr int TROWS = 64;               // sc rows staged per tile (8 KB)
constexpr int NT    = 4;                // tiles per block
constexpr int BROWS = TROWS * NT;       // 256 rows per block

__device__ __forceinline__ int serp_src(int d) {
    int r = d / SDIM;
    int c = d - r * SDIM;
    return (r & 1) ? (r * SDIM + (SDIM - 1 - c)) : d;
}

__global__ __launch_bounds__(256) void serp_decode(
    const float* __restrict__ sc,     // [B, 32]
    const float* __restrict__ dict,   // [900, 32]
    float* __restrict__ out,          // [B, 900]
    int B)
{
    __shared__ float lds[2][TROWS * KD];   // 2 x 8 KB double buffer

    const int t    = threadIdx.x;
    const int lane = t & 63;
    const int wid  = t >> 6;               // wave id 0..3

    const int d1 = blockIdx.x * 256 + t;   // 0..511 (grid.x == 2)
    const int d2 = d1 + 512;               // 512..1023
    const bool v2 = (d2 < DDIM);

    // Pin both (serpentine-remapped) dictionary rows in 64 VGPRs.
    float w1[KD], w2[KD];
    {
        const float4* p = reinterpret_cast<const float4*>(dict + (size_t)serp_src(d1) * KD);
        #pragma unroll
        for (int i = 0; i < KD / 4; ++i) {
            float4 v = p[i];
            w1[4*i+0] = v.x; w1[4*i+1] = v.y; w1[4*i+2] = v.z; w1[4*i+3] = v.w;
        }
        const int s2 = v2 ? serp_src(d2) : 0;
        const float4* q = reinterpret_cast<const float4*>(dict + (size_t)s2 * KD);
        #pragma unroll
        for (int i = 0; i < KD / 4; ++i) {
            float4 v = q[i];
            w2[4*i+0] = v.x; w2[4*i+1] = v.y; w2[4*i+2] = v.z; w2[4*i+3] = v.w;
        }
    }

    const long long b0     = (long long)blockIdx.y * BROWS;
    const long long maxoff = (long long)B * KD - 4;   // clamp (B%BROWS==0 normally)

    // Stage TROWS rows (8 KB) into lds[buf]: 8 chunks of 1 KB; wave `wid`
    // issues chunks {wid, wid+4}. LDS dest = wave-uniform chunk base (HW adds
    // lane*16); global src = per-lane address. Linear layouts match.
    auto stage = [&](int buf, int rbase) {
        #pragma unroll
        for (int c = 0; c < 2; ++c) {
            const int ch = wid + 4 * c;                         // chunk 0..7
            long long off = (b0 + rbase) * KD + ch * 256 + lane * 4;
            if (off > maxoff) off = maxoff;
            __builtin_amdgcn_global_load_lds(
                (const __attribute__((address_space(1))) void*)(sc + off),
                (__attribute__((address_space(3))) void*)(&lds[buf][ch * 256]),
                16, 0, 0);
        }
    };

    stage(0, 0);

    float* __restrict__ o1 = out + (size_t)b0 * DDIM + d1;
    int cur = 0;
    __syncthreads();                 // drains vmcnt(0): tile 0 resident

    for (int tile = 0; tile < NT; ++tile) {
        if (tile + 1 < NT) stage(cur ^ 1, (tile + 1) * TROWS);  // in flight all tile

        const float* S = lds[cur];
        #pragma unroll 2
        for (int bb = 0; bb < TROWS; ++bb) {
            const float4* srow = reinterpret_cast<const float4*>(S + bb * KD);
            float a1a = 0.f, a1b = 0.f, a2a = 0.f, a2b = 0.f;
            #pragma unroll
            for (int j = 0; j < KD / 4; ++j) {
                float4 sv = srow[j];               // uniform addr -> broadcast
                a1a = fmaf(sv.x, w1[4*j+0], a1a);
                a1b = fmaf(sv.y, w1[4*j+1], a1b);
                a1a = fmaf(sv.z, w1[4*j+2], a1a);
                a1b = fmaf(sv.w, w1[4*j+3], a1b);
                a2a = fmaf(sv.x, w2[4*j+0], a2a);
                a2b = fmaf(sv.y, w2[4*j+1], a2b);
                a2a = fmaf(sv.z, w2[4*j+2], a2a);
                a2b = fmaf(sv.w, w2[4*j+3], a2b);
            }
            o1[0] = a1a + a1b;                     // coalesced 256B/wave
            if (v2) o1[512] = a2a + a2b;
            o1 += DDIM;
        }
        __syncthreads();             // drains next tile's loads + this tile's reads
        cur ^= 1;
    }
}

extern "C" void kernel_launch(void* const* d_in, const int* in_sizes, int n_in,
                              void* d_out, int out_size, void* d_ws, size_t ws_size,
                              hipStream_t stream) {
    const float* sc   = (const float*)d_in[0];   // [B, 32]
    const float* dict = (const float*)d_in[1];   // [900, 32]
    float* out        = (float*)d_out;           // [B, 1, 30, 30] flat = [B, 900]

    const int B = in_sizes[0] / KD;              // 262144 (divisible by BROWS=256)

    dim3 grid(2, (unsigned)(B / BROWS));
    serp_decode<<<grid, 256, 0, stream>>>(sc, dict, out, B);
}

// Round 5
// 321.230 us; speedup vs baseline: 8.0720x; 1.2325x over previous
//
#include <hip/hip_runtime.h>
#include <hip/hip_bf16.h>

// out[b, d] = sum_k sc[b,k] * dict[serp(d), k]    B=262144, K=32, D=900.
//
// R4 post-mortem: lane=d + LDS-broadcast of sc rows is LDS-pipe-bound:
// 8 ds_read_b128/row x 12cyc on the ONE per-CU LDS pipe shared by 4 SIMDs
// = 328us floor (measured 396). VALU floor (64 fmaf/row) is another 109us.
// R5: bf16 MFMA (threshold 0.82 admits bf16). One mfma_f32_16x16x32_bf16
// = 16x16 outputs, full K=32, ~5cyc. Compute disappears; kernel becomes
// write-BW-bound (944 MB / ~6.8 TB/s ~= 140us, cf. fillBuffer at 6.8 TB/s).
//
// Per block: build serpentine+bf16+fragment-ordered dict chunks in LDS once
// (29KB -> 5 blocks/CU), then per wave: 4 rowgroups x 16 b-rows, per chunk
// {ds_read_b128 B-frag, mfma, 4 stores of 64B segments}. All chunks
// independent -> unroll hides LDS latency.
//
// Fragment layouts (m89-verified convention for 16x16x32 bf16):
//   A: row = lane&15, k = (lane>>4)*8 + j
//   B: col = lane&15, k = (lane>>4)*8 + j
//   C/D: col = lane&15, row = (lane>>4)*4 + reg

typedef __attribute__((ext_vector_type(8))) short bf16x8;
typedef __attribute__((ext_vector_type(4))) float f32x4;

constexpr int KD   = 32;
constexpr int DDIM = 900;
constexpr int SDIM = 30;
constexpr int NCHT = 57;    // total 16-col chunks (57*16 = 912 >= 900)
constexpr int NCH0 = 29;    // chunks in block x=0 (x=1 gets 28)
constexpr int NRG  = 4;     // rowgroups per wave
constexpr int RPB  = 4 * NRG * 16;   // 256 b-rows per block

__device__ __forceinline__ int serp_src(int d) {
    int r = d / SDIM, c = d - r * SDIM;
    return (r & 1) ? (r * SDIM + (SDIM - 1 - c)) : d;
}

__device__ __forceinline__ short f2bf(float x) {
    __hip_bfloat16 h = __float2bfloat16(x);   // RNE
    short u; __builtin_memcpy(&u, &h, 2); return u;
}

__global__ __launch_bounds__(256) void mfma_decode(
    const float* __restrict__ sc,     // [B, 32]
    const float* __restrict__ dict,   // [900, 32]
    float* __restrict__ out,          // [B, 900]
    int B)
{
    __shared__ bf16x8 ldsf[NCH0 * 64];   // 29 KB of B-fragments

    const int t    = threadIdx.x;
    const int lane = t & 63;
    const int wid  = t >> 6;

    const int c0    = blockIdx.x * NCH0;          // 0 or 29
    const int nch   = (NCHT - c0 < NCH0) ? (NCHT - c0) : NCH0;
    const int dbase = c0 * 16;

    // ---- one-time: build dict B-fragments in LDS (serp + bf16 + layout) ----
    for (int u = t; u < nch * 64; u += 256) {
        const int c  = u >> 6;
        const int l  = u & 63;
        const int d  = dbase + (c << 4) + (l & 15);
        const int k0 = (l >> 4) << 3;
        bf16x8 pk;
        if (d < DDIM) {
            const float* p = dict + (size_t)serp_src(d) * KD + k0;
            #pragma unroll
            for (int j = 0; j < 8; ++j) pk[j] = f2bf(p[j]);
        } else {
            #pragma unroll
            for (int j = 0; j < 8; ++j) pk[j] = 0;
        }
        ldsf[(c << 6) + l] = pk;                  // one-time ds_write_b128
    }
    __syncthreads();

    // ---- main: 4 rowgroups of 16 b-rows per wave ----
    const int arow   = lane & 15;                 // A row within group
    const int k0     = (lane >> 4) << 3;          // A/B k offset
    const int colc   = lane & 15;                 // C col
    const int rbase0 = (lane >> 4) << 2;          // C row base (reg i adds)
    const int b0     = blockIdx.y * RPB + wid * (NRG * 16);

    for (int rg = 0; rg < NRG; ++rg) {
        const int rowg = b0 + rg * 16;

        // A-fragment: 8 fp32 -> bf16 per lane.
        const float* ap = sc + (size_t)(rowg + arow) * KD + k0;
        const float4 f0 = *reinterpret_cast<const float4*>(ap);
        const float4 f1 = *reinterpret_cast<const float4*>(ap + 4);
        bf16x8 a;
        a[0] = f2bf(f0.x); a[1] = f2bf(f0.y); a[2] = f2bf(f0.z); a[3] = f2bf(f0.w);
        a[4] = f2bf(f1.x); a[5] = f2bf(f1.y); a[6] = f2bf(f1.z); a[7] = f2bf(f1.w);

        float* obase = out + (size_t)(rowg + rbase0) * DDIM;

        #pragma unroll 4
        for (int n = 0; n < nch; ++n) {
            const bf16x8 bfr = ldsf[(n << 6) + lane];   // ds_read_b128, dense
            f32x4 z = {0.f, 0.f, 0.f, 0.f};
            f32x4 acc = __builtin_amdgcn_mfma_f32_16x16x32_bf16(a, bfr, z, 0, 0, 0);
            const int d = dbase + (n << 4) + colc;
            if (d < DDIM) {                             // masks only chunk 56 tail
                float* o = obase + d;
                #pragma unroll
                for (int i = 0; i < 4; ++i) o[(size_t)i * DDIM] = acc[i];
            }
        }
    }
}

extern "C" void kernel_launch(void* const* d_in, const int* in_sizes, int n_in,
                              void* d_out, int out_size, void* d_ws, size_t ws_size,
                              hipStream_t stream) {
    const float* sc   = (const float*)d_in[0];   // [B, 32]
    const float* dict = (const float*)d_in[1];   // [900, 32]
    float* out        = (float*)d_out;           // [B, 1, 30, 30] flat = [B, 900]

    const int B = in_sizes[0] / KD;              // 262144 (divisible by RPB=256)

    dim3 grid(2, (unsigned)(B / RPB));
    mfma_decode<<<grid, 256, 0, stream>>>(sc, dict, out, B);
}

// Round 6
// 291.136 us; speedup vs baseline: 8.9064x; 1.1034x over previous
//
#include <hip/hip_runtime.h>
#include <hip/hip_bf16.h>

// out[b, d] = sum_k sc[b,k] * dict[serp(d), k]    B=262144, K=32, D=900.
//
// R5 post-mortem: mfma(sc, dict) put C/D as col=lane&15(d), row=(lane>>4)*4+reg(b)
// -> 4 scalar dword stores/lane into 4 different b-rows: 3.69M store instrs,
// 4B/lane. 321us = 2.9 TB/s vs 6.8 TB/s fill ceiling -> store-path-bound.
// R6: OPERAND SWAP. A and B fragments of mfma_f32_16x16x32_bf16 have identical
// lane layouts (m/n = lane&15, k = (lane>>4)*8+j), so mfma(dict_frag, sc_frag)
// is legal with the SAME register/LDS data and flips D to:
//   col(n) = lane&15 -> b-row, row(m) = (lane>>4)*4+reg -> d (4 consecutive!)
// -> one aligned float4 store per lane (16B/lane, 1KB/wave-instr, 4x fewer
// store instructions). Nothing else changes.

typedef __attribute__((ext_vector_type(8))) short bf16x8;
typedef __attribute__((ext_vector_type(4))) float f32x4;

constexpr int KD   = 32;
constexpr int DDIM = 900;
constexpr int SDIM = 30;
constexpr int NCHT = 57;    // total 16-col chunks (57*16 = 912 >= 900)
constexpr int NCH0 = 29;    // chunks in block x=0 (x=1 gets 28)
constexpr int NRG  = 4;     // rowgroups per wave
constexpr int RPB  = 4 * NRG * 16;   // 256 b-rows per block

__device__ __forceinline__ int serp_src(int d) {
    int r = d / SDIM, c = d - r * SDIM;
    return (r & 1) ? (r * SDIM + (SDIM - 1 - c)) : d;
}

__device__ __forceinline__ short f2bf(float x) {
    __hip_bfloat16 h = __float2bfloat16(x);   // RNE
    short u; __builtin_memcpy(&u, &h, 2); return u;
}

__global__ __launch_bounds__(256) void mfma_decode(
    const float* __restrict__ sc,     // [B, 32]
    const float* __restrict__ dict,   // [900, 32]
    float* __restrict__ out,          // [B, 900]
    int B)
{
    __shared__ bf16x8 ldsf[NCH0 * 64];   // 29 KB of dict fragments

    const int t    = threadIdx.x;
    const int lane = t & 63;
    const int wid  = t >> 6;

    const int c0    = blockIdx.x * NCH0;          // 0 or 29
    const int nch   = (NCHT - c0 < NCH0) ? (NCHT - c0) : NCH0;
    const int dbase = c0 * 16;

    // ---- one-time: build dict fragments in LDS (serp + bf16 + layout) ----
    // Fragment at lane l of chunk c: d = dbase + c*16 + (l&15), k = (l>>4)*8 + j.
    for (int u = t; u < nch * 64; u += 256) {
        const int c  = u >> 6;
        const int l  = u & 63;
        const int d  = dbase + (c << 4) + (l & 15);
        const int k0 = (l >> 4) << 3;
        bf16x8 pk;
        if (d < DDIM) {
            const float* p = dict + (size_t)serp_src(d) * KD + k0;
            #pragma unroll
            for (int j = 0; j < 8; ++j) pk[j] = f2bf(p[j]);
        } else {
            #pragma unroll
            for (int j = 0; j < 8; ++j) pk[j] = 0;
        }
        ldsf[(c << 6) + l] = pk;                  // one-time ds_write_b128
    }
    __syncthreads();

    // ---- main: 4 rowgroups of 16 b-rows per wave ----
    const int brow = lane & 15;                   // b-row within group (= D col)
    const int k0   = (lane >> 4) << 3;            // sc-fragment k offset
    const int dloc = (lane >> 4) << 2;            // D row base -> d offset in chunk
    const int b0   = blockIdx.y * RPB + wid * (NRG * 16);

    for (int rg = 0; rg < NRG; ++rg) {
        const int rowg = b0 + rg * 16;

        // sc fragment (B operand): n = lane&15 = b-row, k = (lane>>4)*8 + j.
        const float* ap = sc + (size_t)(rowg + brow) * KD + k0;
        const float4 f0 = *reinterpret_cast<const float4*>(ap);
        const float4 f1 = *reinterpret_cast<const float4*>(ap + 4);
        bf16x8 a;
        a[0] = f2bf(f0.x); a[1] = f2bf(f0.y); a[2] = f2bf(f0.z); a[3] = f2bf(f0.w);
        a[4] = f2bf(f1.x); a[5] = f2bf(f1.y); a[6] = f2bf(f1.z); a[7] = f2bf(f1.w);

        float* __restrict__ orow = out + (size_t)(rowg + brow) * DDIM;  // lane's row

        #pragma unroll 4
        for (int n = 0; n < nch; ++n) {
            const bf16x8 dfr = ldsf[(n << 6) + lane];   // ds_read_b128, dense
            f32x4 z = {0.f, 0.f, 0.f, 0.f};
            // SWAPPED: A = dict (m = d), B = sc (n = b-row).
            f32x4 acc = __builtin_amdgcn_mfma_f32_16x16x32_bf16(dfr, a, z, 0, 0, 0);
            const int d0 = dbase + (n << 4) + dloc;     // 4 consecutive d from here
            if (d0 < DDIM) {                            // 900%4==0: all-or-nothing
                *reinterpret_cast<f32x4*>(orow + d0) = acc;   // 16B aligned
            }
        }
    }
}

extern "C" void kernel_launch(void* const* d_in, const int* in_sizes, int n_in,
                              void* d_out, int out_size, void* d_ws, size_t ws_size,
                              hipStream_t stream) {
    const float* sc   = (const float*)d_in[0];   // [B, 32]
    const float* dict = (const float*)d_in[1];   // [900, 32]
    float* out        = (float*)d_out;           // [B, 1, 30, 30] flat = [B, 900]

    const int B = in_sizes[0] / KD;              // 262144 (divisible by RPB=256)

    dim3 grid(2, (unsigned)(B / RPB));
    mfma_decode<<<grid, 256, 0, stream>>>(sc, dict, out, B);
}

// Round 7
// 232.055 us; speedup vs baseline: 11.1740x; 1.2546x over previous
//
#include <hip/hip_runtime.h>
#include <hip/hip_bf16.h>

// out[b, d] = sum_k sc[b,k] * dict[serp(d), k]    B=262144, K=32, D=900.
//
// R6 post-mortem: mfma D-layout scatters each wave-store into 16 x 64B
// segments at 3600B row stride (3600 % 128 != 0 -> all misaligned). R5 vs R6
// showed segment count, not instruction count, governs time -> line-granularity
// bound at ~3.2 TB/s vs 6.8 TB/s fill ceiling (fill does it at 11% occupancy).
// R7: block owns WHOLE rows -> its output span is fully contiguous. Compute
// unchanged (mfma(dict_frag, sc_frag)); D-tiles staged in LDS [16][464] (29KB,
// 5 blocks/CU), then streamed out as flat, aligned, 1KB-contiguous dwordx4
// writes -- exactly the fill pattern. Dict fragments live in registers
// (wave w owns chunks w+4j, j=0..14; statically indexed).

typedef __attribute__((ext_vector_type(8))) short bf16x8;
typedef __attribute__((ext_vector_type(4))) float f32x4;

constexpr int KD    = 32;
constexpr int DDIM  = 900;
constexpr int SDIM  = 30;
constexpr int NCHT  = 57;              // 16-col chunks (57*16 = 912)
constexpr int TROWS = 16;              // rows per tile (= MFMA n)
constexpr int TILES = 8;               // tiles per block
constexpr int RPB   = TROWS * TILES;   // 128 rows per block
constexpr int STGW  = 464;             // staging width in floats (29 chunks)

__device__ __forceinline__ int serp_src(int d) {
    int r = d / SDIM, c = d - r * SDIM;
    return (r & 1) ? (r * SDIM + (SDIM - 1 - c)) : d;
}

__device__ __forceinline__ short f2bf(float x) {
    __hip_bfloat16 h = __float2bfloat16(x);   // RNE
    short u; __builtin_memcpy(&u, &h, 2); return u;
}

__global__ __launch_bounds__(256) void mfma_decode(
    const float* __restrict__ sc,     // [B, 32]
    const float* __restrict__ dict,   // [900, 32]
    float* __restrict__ out,          // [B, 900]
    int B)
{
    __shared__ alignas(16) float stg[TROWS * STGW];   // 29 KB staging

    const int t    = threadIdx.x;
    const int lane = t & 63;
    const int wid  = t >> 6;

    // ---- dict fragments in registers: wave wid owns chunks wid + 4j ----
    // A-fragment layout: m = lane&15 (-> d within chunk), k = (lane>>4)*8 + j.
    bf16x8 df[15];
    #pragma unroll
    for (int j = 0; j < 15; ++j) {
        int ch = wid + 4 * j; if (ch > NCHT - 1) ch = NCHT - 1;   // dup, unused
        int d  = ch * 16 + (lane & 15);
        int dd = (d < DDIM) ? d : (DDIM - 1);                     // pad lanes
        const float* p = dict + (size_t)serp_src(dd) * KD + ((lane >> 4) << 3);
        const float4 f0 = *reinterpret_cast<const float4*>(p);
        const float4 f1 = *reinterpret_cast<const float4*>(p + 4);
        bf16x8 a;
        a[0] = f2bf(f0.x); a[1] = f2bf(f0.y); a[2] = f2bf(f0.z); a[3] = f2bf(f0.w);
        a[4] = f2bf(f1.x); a[5] = f2bf(f1.y); a[6] = f2bf(f1.z); a[7] = f2bf(f1.w);
        df[j] = a;
    }

    const int brow = lane & 15;             // D col (n) -> b-row
    const int k0   = (lane >> 4) << 3;      // sc fragment k offset
    const int dloc = (lane >> 4) << 2;      // D row (m) base -> d offset in chunk
    const long long b0 = (long long)blockIdx.x * RPB;

    for (int tile = 0; tile < TILES; ++tile) {
        const long long rowg = b0 + (long long)tile * TROWS;

        // sc fragment (B operand): n = lane&15 = b-row, k = (lane>>4)*8 + j.
        const float* ap = sc + (size_t)(rowg + brow) * KD + k0;
        const float4 f0 = *reinterpret_cast<const float4*>(ap);
        const float4 f1 = *reinterpret_cast<const float4*>(ap + 4);
        bf16x8 bb;
        bb[0] = f2bf(f0.x); bb[1] = f2bf(f0.y); bb[2] = f2bf(f0.z); bb[3] = f2bf(f0.w);
        bb[4] = f2bf(f1.x); bb[5] = f2bf(f1.y); bb[6] = f2bf(f1.z); bb[7] = f2bf(f1.w);

        float* __restrict__ tbase = out + (size_t)rowg * DDIM;

        #pragma unroll
        for (int P = 0; P < 2; ++P) {
            // ---- compute phase: my chunks in this d-half -> staging ----
            #pragma unroll
            for (int j = 0; j < 15; ++j) {
                const int ch = wid + 4 * j;
                const bool mine = (P == 0) ? (ch < 28) : (ch >= 28 && ch < NCHT);
                if (mine) {
                    f32x4 z = {0.f, 0.f, 0.f, 0.f};
                    f32x4 acc = __builtin_amdgcn_mfma_f32_16x16x32_bf16(df[j], bb, z, 0, 0, 0);
                    const int dl = ch * 16 + dloc - P * 448;   // chunk56 tail -> padding
                    *reinterpret_cast<f32x4*>(&stg[brow * STGW + dl]) = acc;
                }
            }
            __syncthreads();

            // ---- write phase: flat contiguous dwordx4 stream (fill pattern) ----
            if (P == 0) {
                // 16 rows x 112 float4 (floats 0..447) = 1792 = 7 * 256, exact.
                #pragma unroll
                for (int i = 0; i < 7; ++i) {
                    const int idx = i * 256 + t;
                    const int row = idx / 112;
                    const int c4  = idx - row * 112;
                    f32x4 v = *reinterpret_cast<const f32x4*>(&stg[row * STGW + c4 * 4]);
                    *reinterpret_cast<f32x4*>(tbase + (size_t)row * DDIM + c4 * 4) = v;
                }
            } else {
                // 16 rows x 113 float4 (floats 448..899) = 1808; 8 iters, guarded.
                #pragma unroll
                for (int i = 0; i < 8; ++i) {
                    const int idx = i * 256 + t;
                    if (idx < 1808) {
                        const int row = idx / 113;
                        const int c4  = idx - row * 113;
                        f32x4 v = *reinterpret_cast<const f32x4*>(&stg[row * STGW + c4 * 4]);
                        *reinterpret_cast<f32x4*>(tbase + (size_t)row * DDIM + 448 + c4 * 4) = v;
                    }
                }
            }
            __syncthreads();   // staging reusable for next phase/tile
        }
    }
}

extern "C" void kernel_launch(void* const* d_in, const int* in_sizes, int n_in,
                              void* d_out, int out_size, void* d_ws, size_t ws_size,
                              hipStream_t stream) {
    const float* sc   = (const float*)d_in[0];   // [B, 32]
    const float* dict = (const float*)d_in[1];   // [900, 32]
    float* out        = (float*)d_out;           // [B, 1, 30, 30] flat = [B, 900]

    const int B = in_sizes[0] / KD;              // 262144 (divisible by RPB=128)

    mfma_decode<<<dim3((unsigned)(B / RPB)), 256, 0, stream>>>(sc, dict, out, B);
}

// Round 8
// 219.170 us; speedup vs baseline: 11.8309x; 1.0588x over previous
//
#include <hip/hip_runtime.h>
#include <hip/hip_bf16.h>

// out[b, d] = sum_k sc[b,k] * dict[serp(d), k]    B=262144, K=32, D=900.
//
// R7 post-mortem: 232us = 4.0 TB/s vs 6.8 TB/s fill ceiling. The write phase
// IS the fill pattern, but __syncthreads() => s_waitcnt vmcnt(0) before
// s_barrier -> every phase waits for global-store drain, store pipe idles
// during compute (store duty ~60%). Barriers only need to order LDS.
// R8: (1) lgkmcnt-only barriers (raw s_barrier; vmcnt NEVER drains in the
// loop -- store-queue backpressure is the throttle, exactly like fill);
// (2) 1-deep register prefetch of next tile's sc fragment so the per-tile
// sc load latency hides under current tile's compute+write.

typedef __attribute__((ext_vector_type(8))) short bf16x8;
typedef __attribute__((ext_vector_type(4))) float f32x4;

constexpr int KD    = 32;
constexpr int DDIM  = 900;
constexpr int SDIM  = 30;
constexpr int NCHT  = 57;              // 16-col chunks (57*16 = 912)
constexpr int TROWS = 16;              // rows per tile (= MFMA n)
constexpr int TILES = 8;               // tiles per block
constexpr int RPB   = TROWS * TILES;   // 128 rows per block
constexpr int STGW  = 464;             // staging width in floats (29 chunks)

__device__ __forceinline__ int serp_src(int d) {
    int r = d / SDIM, c = d - r * SDIM;
    return (r & 1) ? (r * SDIM + (SDIM - 1 - c)) : d;
}

__device__ __forceinline__ short f2bf(float x) {
    __hip_bfloat16 h = __float2bfloat16(x);   // RNE
    short u; __builtin_memcpy(&u, &h, 2); return u;
}

// Barrier that orders LDS only: waits ds ops, does NOT drain the global-store
// queue (vmcnt stays outstanding across it -- the whole point).
__device__ __forceinline__ void barrier_lds() {
    __builtin_amdgcn_sched_barrier(0);
    asm volatile("s_waitcnt lgkmcnt(0)" ::: "memory");
    __builtin_amdgcn_sched_barrier(0);
    __builtin_amdgcn_s_barrier();
    __builtin_amdgcn_sched_barrier(0);
}

__global__ __launch_bounds__(256) void mfma_decode(
    const float* __restrict__ sc,     // [B, 32]
    const float* __restrict__ dict,   // [900, 32]
    float* __restrict__ out,          // [B, 900]
    int B)
{
    __shared__ alignas(16) float stg[TROWS * STGW];   // 29 KB staging

    const int t    = threadIdx.x;
    const int lane = t & 63;
    const int wid  = t >> 6;

    // ---- dict fragments in registers: wave wid owns chunks wid + 4j ----
    // A-fragment layout: m = lane&15 (-> d within chunk), k = (lane>>4)*8 + j.
    bf16x8 df[15];
    #pragma unroll
    for (int j = 0; j < 15; ++j) {
        int ch = wid + 4 * j; if (ch > NCHT - 1) ch = NCHT - 1;   // dup, unused
        int d  = ch * 16 + (lane & 15);
        int dd = (d < DDIM) ? d : (DDIM - 1);                     // pad lanes
        const float* p = dict + (size_t)serp_src(dd) * KD + ((lane >> 4) << 3);
        const float4 f0 = *reinterpret_cast<const float4*>(p);
        const float4 f1 = *reinterpret_cast<const float4*>(p + 4);
        bf16x8 a;
        a[0] = f2bf(f0.x); a[1] = f2bf(f0.y); a[2] = f2bf(f0.z); a[3] = f2bf(f0.w);
        a[4] = f2bf(f1.x); a[5] = f2bf(f1.y); a[6] = f2bf(f1.z); a[7] = f2bf(f1.w);
        df[j] = a;
    }

    const int brow = lane & 15;             // D col (n) -> b-row
    const int k0   = (lane >> 4) << 3;      // sc fragment k offset
    const int dloc = (lane >> 4) << 2;      // D row (m) base -> d offset in chunk
    const long long b0 = (long long)blockIdx.x * RPB;

    // Prefetch tile 0's sc fragment.
    const float* ap0 = sc + (size_t)(b0 + brow) * KD + k0;
    float4 pf0 = *reinterpret_cast<const float4*>(ap0);
    float4 pf1 = *reinterpret_cast<const float4*>(ap0 + 4);

    for (int tile = 0; tile < TILES; ++tile) {
        const long long rowg = b0 + (long long)tile * TROWS;

        // Consume prefetched sc fragment (B operand): n=lane&15=b-row.
        bf16x8 bb;
        bb[0] = f2bf(pf0.x); bb[1] = f2bf(pf0.y); bb[2] = f2bf(pf0.z); bb[3] = f2bf(pf0.w);
        bb[4] = f2bf(pf1.x); bb[5] = f2bf(pf1.y); bb[6] = f2bf(pf1.z); bb[7] = f2bf(pf1.w);

        // Issue next tile's sc loads now; latency hides under compute+write.
        if (tile + 1 < TILES) {
            const float* apn = sc + (size_t)(rowg + TROWS + brow) * KD + k0;
            pf0 = *reinterpret_cast<const float4*>(apn);
            pf1 = *reinterpret_cast<const float4*>(apn + 4);
        }

        float* __restrict__ tbase = out + (size_t)rowg * DDIM;

        #pragma unroll
        for (int P = 0; P < 2; ++P) {
            // ---- compute phase: my chunks in this d-half -> staging ----
            #pragma unroll
            for (int j = 0; j < 15; ++j) {
                const int ch = wid + 4 * j;
                const bool mine = (P == 0) ? (ch < 28) : (ch >= 28 && ch < NCHT);
                if (mine) {
                    f32x4 z = {0.f, 0.f, 0.f, 0.f};
                    f32x4 acc = __builtin_amdgcn_mfma_f32_16x16x32_bf16(df[j], bb, z, 0, 0, 0);
                    const int dl = ch * 16 + dloc - P * 448;   // chunk56 tail -> padding
                    *reinterpret_cast<f32x4*>(&stg[brow * STGW + dl]) = acc;
                }
            }
            barrier_lds();   // staging visible; global stores stay in flight

            // ---- write phase: flat contiguous dwordx4 stream (fill pattern) ----
            if (P == 0) {
                // 16 rows x 112 float4 (floats 0..447) = 1792 = 7 * 256, exact.
                #pragma unroll
                for (int i = 0; i < 7; ++i) {
                    const int idx = i * 256 + t;
                    const int row = idx / 112;
                    const int c4  = idx - row * 112;
                    f32x4 v = *reinterpret_cast<const f32x4*>(&stg[row * STGW + c4 * 4]);
                    *reinterpret_cast<f32x4*>(tbase + (size_t)row * DDIM + c4 * 4) = v;
                }
            } else {
                // 16 rows x 113 float4 (floats 448..899) = 1808; 8 iters, guarded.
                #pragma unroll
                for (int i = 0; i < 8; ++i) {
                    const int idx = i * 256 + t;
                    if (idx < 1808) {
                        const int row = idx / 113;
                        const int c4  = idx - row * 113;
                        f32x4 v = *reinterpret_cast<const f32x4*>(&stg[row * STGW + c4 * 4]);
                        *reinterpret_cast<f32x4*>(tbase + (size_t)row * DDIM + 448 + c4 * 4) = v;
                    }
                }
            }
            barrier_lds();   // staging reusable; stores still in flight
        }
    }
}

extern "C" void kernel_launch(void* const* d_in, const int* in_sizes, int n_in,
                              void* d_out, int out_size, void* d_ws, size_t ws_size,
                              hipStream_t stream) {
    const float* sc   = (const float*)d_in[0];   // [B, 32]
    const float* dict = (const float*)d_in[1];   // [900, 32]
    float* out        = (float*)d_out;           // [B, 1, 30, 30] flat = [B, 900]

    const int B = in_sizes[0] / KD;              // 262144 (divisible by RPB=128)

    mfma_decode<<<dim3((unsigned)(B / RPB)), 256, 0, stream>>>(sc, dict, out, B);
}

// Round 9
// 203.318 us; speedup vs baseline: 12.7534x; 1.0780x over previous
//
#include <hip/hip_runtime.h>
#include <hip/hip_bf16.h>

// out[b, d] = sum_k sc[b,k] * dict[serp(d), k]    B=262144, K=32, D=900.
//
// R8 post-mortem: lgkm-only barriers bought only 13us (232->219). Remaining
// structural costs: half-row segments (1792B at 3600B stride: misaligned
// edges, same 128B line touched in two phases), ~10 VALU/iter of div-magic
// addressing in the write loop, 4 barriers/tile.
// R9: stage the FULL 16x900 tile in LDS (57.6KB, 2 blocks/CU). The block's
// output span is contiguous, so the write phase is a literal fill pattern:
// out[tbase+o] = stg[o], o = i*1024 + t*4 -- no division, 14 unguarded
// float4 iterations + 16-thread epilogue, one monotonic contiguous stream.
// Barriers drop to 2/tile (still lgkm-only; stores never drain in-loop).
// Compute: all 57 chunks per tile (wave w owns chunks w+4j); chunk 56's
// d>=900 spill masked to dloc==0 lanes. stg stride 900 floats -> 2-way
// write aliasing per 16-lane phase (free, m136); copy reads flat.

typedef __attribute__((ext_vector_type(8))) short bf16x8;
typedef __attribute__((ext_vector_type(4))) float f32x4;

constexpr int KD    = 32;
constexpr int DDIM  = 900;
constexpr int SDIM  = 30;
constexpr int NCHT  = 57;              // 16-col chunks (57*16 = 912)
constexpr int TROWS = 16;              // rows per tile (= MFMA n)
constexpr int TILES = 8;               // tiles per block
constexpr int RPB   = TROWS * TILES;   // 128 rows per block

__device__ __forceinline__ int serp_src(int d) {
    int r = d / SDIM, c = d - r * SDIM;
    return (r & 1) ? (r * SDIM + (SDIM - 1 - c)) : d;
}

__device__ __forceinline__ short f2bf(float x) {
    __hip_bfloat16 h = __float2bfloat16(x);   // RNE
    short u; __builtin_memcpy(&u, &h, 2); return u;
}

// Barrier ordering LDS only: waits own ds ops, does NOT drain global stores.
__device__ __forceinline__ void barrier_lds() {
    __builtin_amdgcn_sched_barrier(0);
    asm volatile("s_waitcnt lgkmcnt(0)" ::: "memory");
    __builtin_amdgcn_sched_barrier(0);
    __builtin_amdgcn_s_barrier();
    __builtin_amdgcn_sched_barrier(0);
}

__global__ __launch_bounds__(256) void mfma_decode(
    const float* __restrict__ sc,     // [B, 32]
    const float* __restrict__ dict,   // [900, 32]
    float* __restrict__ out,          // [B, 900]
    int B)
{
    __shared__ alignas(16) float stg[TROWS * DDIM];   // 57600 B full tile

    const int t    = threadIdx.x;
    const int lane = t & 63;
    const int wid  = t >> 6;

    // ---- dict fragments in registers: wave wid owns chunks wid + 4j ----
    // A-fragment layout: m = lane&15 (-> d within chunk), k = (lane>>4)*8 + j.
    bf16x8 df[15];
    #pragma unroll
    for (int j = 0; j < 15; ++j) {
        int ch = wid + 4 * j; if (ch > NCHT - 1) ch = NCHT - 1;   // dup, unused
        int d  = ch * 16 + (lane & 15);
        int dd = (d < DDIM) ? d : (DDIM - 1);                     // pad lanes
        const float* p = dict + (size_t)serp_src(dd) * KD + ((lane >> 4) << 3);
        const float4 f0 = *reinterpret_cast<const float4*>(p);
        const float4 f1 = *reinterpret_cast<const float4*>(p + 4);
        bf16x8 a;
        a[0] = f2bf(f0.x); a[1] = f2bf(f0.y); a[2] = f2bf(f0.z); a[3] = f2bf(f0.w);
        a[4] = f2bf(f1.x); a[5] = f2bf(f1.y); a[6] = f2bf(f1.z); a[7] = f2bf(f1.w);
        df[j] = a;
    }

    const int brow = lane & 15;             // D col (n) -> b-row within tile
    const int k0   = (lane >> 4) << 3;      // sc fragment k offset
    const int dloc = (lane >> 4) << 2;      // D row (m) base -> d offset in chunk
    const long long b0 = (long long)blockIdx.x * RPB;

    // Prefetch tile 0's sc fragment.
    const float* ap0 = sc + (size_t)(b0 + brow) * KD + k0;
    float4 pf0 = *reinterpret_cast<const float4*>(ap0);
    float4 pf1 = *reinterpret_cast<const float4*>(ap0 + 4);

    for (int tile = 0; tile < TILES; ++tile) {
        const long long rowg = b0 + (long long)tile * TROWS;

        // Consume prefetched sc fragment (B operand): n = lane&15 = b-row.
        bf16x8 bb;
        bb[0] = f2bf(pf0.x); bb[1] = f2bf(pf0.y); bb[2] = f2bf(pf0.z); bb[3] = f2bf(pf0.w);
        bb[4] = f2bf(pf1.x); bb[5] = f2bf(pf1.y); bb[6] = f2bf(pf1.z); bb[7] = f2bf(pf1.w);

        // Issue next tile's sc loads; latency hides under compute+copy.
        if (tile + 1 < TILES) {
            const float* apn = sc + (size_t)(rowg + TROWS + brow) * KD + k0;
            pf0 = *reinterpret_cast<const float4*>(apn);
            pf1 = *reinterpret_cast<const float4*>(apn + 4);
        }

        // ---- compute phase: all my chunks -> full-tile staging ----
        #pragma unroll
        for (int j = 0; j < 15; ++j) {
            const int ch = wid + 4 * j;
            if (ch < NCHT) {                         // wave-uniform
                f32x4 z = {0.f, 0.f, 0.f, 0.f};
                f32x4 acc = __builtin_amdgcn_mfma_f32_16x16x32_bf16(df[j], bb, z, 0, 0, 0);
                if (ch != 56) {
                    *reinterpret_cast<f32x4*>(&stg[brow * DDIM + ch * 16 + dloc]) = acc;
                } else if (dloc == 0) {              // only d=896..899 valid
                    *reinterpret_cast<f32x4*>(&stg[brow * DDIM + 896]) = acc;
                }
            }
        }
        barrier_lds();   // staging visible; global stores stay in flight

        // ---- copy phase: literal fill pattern, fully contiguous ----
        float* __restrict__ tbase = out + (size_t)rowg * DDIM;
        const int base = t * 4;
        #pragma unroll
        for (int i = 0; i < 14; ++i) {
            const int o = i * 1024 + base;           // floats; 14*1024 = 14336
            f32x4 v = *reinterpret_cast<const f32x4*>(&stg[o]);
            *reinterpret_cast<f32x4*>(tbase + o) = v;
        }
        if (t < 16) {                                // 14336 + 64 = 14400 = 16*900
            const int o = 14336 + base;
            f32x4 v = *reinterpret_cast<const f32x4*>(&stg[o]);
            *reinterpret_cast<f32x4*>(tbase + o) = v;
        }
        barrier_lds();   // staging reusable; stores still in flight
    }
}

extern "C" void kernel_launch(void* const* d_in, const int* in_sizes, int n_in,
                              void* d_out, int out_size, void* d_ws, size_t ws_size,
                              hipStream_t stream) {
    const float* sc   = (const float*)d_in[0];   // [B, 32]
    const float* dict = (const float*)d_in[1];   // [900, 32]
    float* out        = (float*)d_out;           // [B, 1, 30, 30] flat = [B, 900]

    const int B = in_sizes[0] / KD;              // 262144 (divisible by RPB=128)

    mfma_decode<<<dim3((unsigned)(B / RPB)), 256, 0, stream>>>(sc, dict, out, B);
}

// Round 10
// 201.925 us; speedup vs baseline: 12.8414x; 1.0069x over previous
//
#include <hip/hip_runtime.h>
#include <hip/hip_bf16.h>

// out[b, d] = sum_k sc[b,k] * dict[serp(d), k]    B=262144, K=32, D=900.
//
// R9 post-mortem: full-tile staging + fill-pattern copy + lgkm-only barriers
// = 203us (4.6 TB/s vs 6.8 fill ceiling). Residual = intra-block alternation:
// compute -> barrier -> copy -> barrier pauses each block's store stream every
// tile; 2 blocks/CU can phase-lock -> ~68% store duty.
// R10: DOUBLE-BUFFER the staging (2 x 57.6 KB = 115.2 KB LDS, 1 block/CU).
// Per tile: compute(t+1) into buf[cur^1] (MFMA+ds_write) runs back-to-back
// with copy(t) from buf[cur] (ds_read+store) -- disjoint buffers, no
// intra-tile wait, ONE lgkm-only barrier per tile. Stores never drain in-loop
// (sc prefetch is 2-deep; compiler emits counted vmcnt). 4 waves/CU is enough
// for store saturation (fill: 6.8 TB/s at ~3.5 waves/CU).

typedef __attribute__((ext_vector_type(8))) short bf16x8;
typedef __attribute__((ext_vector_type(4))) float f32x4;

constexpr int KD    = 32;
constexpr int DDIM  = 900;
constexpr int SDIM  = 30;
constexpr int NCHT  = 57;              // 16-col chunks (57*16 = 912)
constexpr int TROWS = 16;              // rows per tile (= MFMA n)
constexpr int TILES = 16;              // tiles per block
constexpr int RPB   = TROWS * TILES;   // 256 rows per block -> 1024 blocks
constexpr int TFL   = TROWS * DDIM;    // 14400 floats per staging buffer

__device__ __forceinline__ int serp_src(int d) {
    int r = d / SDIM, c = d - r * SDIM;
    return (r & 1) ? (r * SDIM + (SDIM - 1 - c)) : d;
}

__device__ __forceinline__ short f2bf(float x) {
    __hip_bfloat16 h = __float2bfloat16(x);   // RNE
    short u; __builtin_memcpy(&u, &h, 2); return u;
}

// Barrier ordering LDS only: waits own ds ops, does NOT drain global stores.
__device__ __forceinline__ void barrier_lds() {
    __builtin_amdgcn_sched_barrier(0);
    asm volatile("s_waitcnt lgkmcnt(0)" ::: "memory");
    __builtin_amdgcn_sched_barrier(0);
    __builtin_amdgcn_s_barrier();
    __builtin_amdgcn_sched_barrier(0);
}

__global__ __launch_bounds__(256) void mfma_decode(
    const float* __restrict__ sc,     // [B, 32]
    const float* __restrict__ dict,   // [900, 32]
    float* __restrict__ out,          // [B, 900]
    int B)
{
    __shared__ alignas(16) float stg[2][TFL];   // 115200 B double buffer

    const int t    = threadIdx.x;
    const int lane = t & 63;
    const int wid  = t >> 6;

    // ---- dict fragments in registers: wave wid owns chunks wid + 4j ----
    // A-fragment layout: m = lane&15 (-> d within chunk), k = (lane>>4)*8 + j.
    bf16x8 df[15];
    #pragma unroll
    for (int j = 0; j < 15; ++j) {
        int ch = wid + 4 * j; if (ch > NCHT - 1) ch = NCHT - 1;   // dup, unused
        int d  = ch * 16 + (lane & 15);
        int dd = (d < DDIM) ? d : (DDIM - 1);                     // pad lanes
        const float* p = dict + (size_t)serp_src(dd) * KD + ((lane >> 4) << 3);
        const float4 f0 = *reinterpret_cast<const float4*>(p);
        const float4 f1 = *reinterpret_cast<const float4*>(p + 4);
        bf16x8 a;
        a[0] = f2bf(f0.x); a[1] = f2bf(f0.y); a[2] = f2bf(f0.z); a[3] = f2bf(f0.w);
        a[4] = f2bf(f1.x); a[5] = f2bf(f1.y); a[6] = f2bf(f1.z); a[7] = f2bf(f1.w);
        df[j] = a;
    }

    const int brow = lane & 15;             // D col (n) -> b-row within tile
    const int k0   = (lane >> 4) << 3;      // sc fragment k offset
    const int dloc = (lane >> 4) << 2;      // D row (m) base -> d offset in chunk
    const long long b0 = (long long)blockIdx.x * RPB;

    // MFMA pass for one tile: sc fragment bbx -> staging buffer buf.
    auto compute = [&](const bf16x8& bbx, float* buf) {
        #pragma unroll
        for (int j = 0; j < 15; ++j) {
            const int ch = wid + 4 * j;
            if (ch < NCHT) {                         // wave-uniform
                f32x4 z = {0.f, 0.f, 0.f, 0.f};
                f32x4 acc = __builtin_amdgcn_mfma_f32_16x16x32_bf16(df[j], bbx, z, 0, 0, 0);
                if (ch != 56) {
                    *reinterpret_cast<f32x4*>(&buf[brow * DDIM + ch * 16 + dloc]) = acc;
                } else if (dloc == 0) {              // only d=896..899 valid
                    *reinterpret_cast<f32x4*>(&buf[brow * DDIM + 896]) = acc;
                }
            }
        }
    };

    // sc fragment load for tile tt (2 x float4 per lane).
    auto sc_load = [&](int tt, float4& a, float4& b) {
        const float* ap = sc + (size_t)(b0 + tt * TROWS + brow) * KD + k0;
        a = *reinterpret_cast<const float4*>(ap);
        b = *reinterpret_cast<const float4*>(ap + 4);
    };
    auto sc_cvt = [&](const float4& a, const float4& b) {
        bf16x8 r;
        r[0] = f2bf(a.x); r[1] = f2bf(a.y); r[2] = f2bf(a.z); r[3] = f2bf(a.w);
        r[4] = f2bf(b.x); r[5] = f2bf(b.y); r[6] = f2bf(b.z); r[7] = f2bf(b.w);
        return r;
    };

    // Prologue: tile 0 computed into buf 0; tile 1's sc load in flight.
    float4 pf0, pf1;
    sc_load(0, pf0, pf1);
    bf16x8 bb0 = sc_cvt(pf0, pf1);
    sc_load(1, pf0, pf1);
    compute(bb0, stg[0]);
    barrier_lds();

    int cur = 0;
    const int base = t * 4;

    for (int tile = 0; tile < TILES; ++tile) {
        // ---- compute tile+1 into buf[cur^1] (MFMA + ds_write pipes) ----
        if (tile + 1 < TILES) {
            bf16x8 nb = sc_cvt(pf0, pf1);            // waits its load (counted vmcnt)
            if (tile + 2 < TILES) sc_load(tile + 2, pf0, pf1);
            compute(nb, stg[cur ^ 1]);
        }

        // ---- copy tile from buf[cur]: literal fill pattern ----
        float* __restrict__ tbase = out + (size_t)(b0 + (long long)tile * TROWS) * DDIM;
        const float* __restrict__ buf = stg[cur];
        #pragma unroll
        for (int i = 0; i < 14; ++i) {
            const int o = i * 1024 + base;           // 14*1024 = 14336
            f32x4 v = *reinterpret_cast<const f32x4*>(&buf[o]);
            *reinterpret_cast<f32x4*>(tbase + o) = v;
        }
        if (t < 16) {                                // 14336 + 64 = 14400
            const int o = 14336 + base;
            f32x4 v = *reinterpret_cast<const f32x4*>(&buf[o]);
            *reinterpret_cast<f32x4*>(tbase + o) = v;
        }

        barrier_lds();   // buf[cur^1] writes visible; buf[cur] reads retired
        cur ^= 1;        // stores stay in flight across the barrier
    }
}

extern "C" void kernel_launch(void* const* d_in, const int* in_sizes, int n_in,
                              void* d_out, int out_size, void* d_ws, size_t ws_size,
                              hipStream_t stream) {
    const float* sc   = (const float*)d_in[0];   // [B, 32]
    const float* dict = (const float*)d_in[1];   // [900, 32]
    float* out        = (float*)d_out;           // [B, 1, 30, 30] flat = [B, 900]

    const int B = in_sizes[0] / KD;              // 262144 (divisible by RPB=256)

    mfma_decode<<<dim3((unsigned)(B / RPB)), 256, 0, stream>>>(sc, dict, out, B);
}

// Round 11
// 194.309 us; speedup vs baseline: 13.3446x; 1.0392x over previous
//
#include <hip/hip_runtime.h>
#include <hip/hip_bf16.h>

// out[b, d] = sum_k sc[b,k] * dict[serp(d), k]    B=262144, K=32, D=900.
//
// R10 post-mortem: double-buffer null (203->202) -> alternation wasn't the
// limiter. Remaining mechanism: vmcnt FIFO hazard. Per tile, the sc-fragment
// s_waitcnt vmcnt(N) sits BEHIND the previous tile's stores in the single
// vmcnt FIFO, so it drains the store queue to ~15 outstanding once per tile
// -> average queue depth (and thus achieved write BW) collapses to ~4.6 TB/s
// vs fill's 6.8 (fill never waits vmcnt).
// R11: preload ALL 16 tiles' sc fragments into registers in the prologue
// (bb[16] = 64 VGPR, statically indexed by full unroll; launch_bounds(256,1)
// so the allocator has the full 512-reg budget and never spills). The steady
// loop has ZERO vmem reads and ZERO vmcnt waits: stores ride the queue at max
// depth, pure backpressure -- the fill pattern exactly. sc is also now read
// exactly once (FETCH ~36 MB).

typedef __attribute__((ext_vector_type(8))) short bf16x8;
typedef __attribute__((ext_vector_type(4))) float f32x4;

constexpr int KD    = 32;
constexpr int DDIM  = 900;
constexpr int SDIM  = 30;
constexpr int NCHT  = 57;              // 16-col chunks (57*16 = 912)
constexpr int TROWS = 16;              // rows per tile (= MFMA n)
constexpr int TILES = 16;              // tiles per block
constexpr int RPB   = TROWS * TILES;   // 256 rows per block -> 1024 blocks
constexpr int TFL   = TROWS * DDIM;    // 14400 floats per staging buffer

__device__ __forceinline__ int serp_src(int d) {
    int r = d / SDIM, c = d - r * SDIM;
    return (r & 1) ? (r * SDIM + (SDIM - 1 - c)) : d;
}

__device__ __forceinline__ short f2bf(float x) {
    __hip_bfloat16 h = __float2bfloat16(x);   // RNE
    short u; __builtin_memcpy(&u, &h, 2); return u;
}

// Barrier ordering LDS only: waits own ds ops, does NOT drain global stores.
__device__ __forceinline__ void barrier_lds() {
    __builtin_amdgcn_sched_barrier(0);
    asm volatile("s_waitcnt lgkmcnt(0)" ::: "memory");
    __builtin_amdgcn_sched_barrier(0);
    __builtin_amdgcn_s_barrier();
    __builtin_amdgcn_sched_barrier(0);
}

__global__ __launch_bounds__(256, 1) void mfma_decode(
    const float* __restrict__ sc,     // [B, 32]
    const float* __restrict__ dict,   // [900, 32]
    float* __restrict__ out,          // [B, 900]
    int B)
{
    __shared__ alignas(16) float stg[2][TFL];   // 115200 B double buffer

    const int t    = threadIdx.x;
    const int lane = t & 63;
    const int wid  = t >> 6;

    const int brow = lane & 15;             // D col (n) -> b-row within tile
    const int k0   = (lane >> 4) << 3;      // fragment k offset
    const int dloc = (lane >> 4) << 2;      // D row (m) base -> d offset in chunk
    const long long b0 = (long long)blockIdx.x * RPB;

    // ---- prologue 1: issue ALL sc loads (16 tiles x 2 float4 per lane) ----
    float4 ra[TILES], rb[TILES];
    #pragma unroll
    for (int tt = 0; tt < TILES; ++tt) {
        const float* ap = sc + (size_t)(b0 + tt * TROWS + brow) * KD + k0;
        ra[tt] = *reinterpret_cast<const float4*>(ap);
        rb[tt] = *reinterpret_cast<const float4*>(ap + 4);
    }

    // ---- prologue 2: dict fragments df[15]: wave wid owns chunks wid+4j ----
    // A-fragment layout: m = lane&15 (-> d within chunk), k = (lane>>4)*8 + j.
    bf16x8 df[15];
    #pragma unroll
    for (int j = 0; j < 15; ++j) {
        int ch = wid + 4 * j; if (ch > NCHT - 1) ch = NCHT - 1;   // dup, unused
        int d  = ch * 16 + (lane & 15);
        int dd = (d < DDIM) ? d : (DDIM - 1);                     // pad lanes
        const float* p = dict + (size_t)serp_src(dd) * KD + k0;
        const float4 f0 = *reinterpret_cast<const float4*>(p);
        const float4 f1 = *reinterpret_cast<const float4*>(p + 4);
        bf16x8 a;
        a[0] = f2bf(f0.x); a[1] = f2bf(f0.y); a[2] = f2bf(f0.z); a[3] = f2bf(f0.w);
        a[4] = f2bf(f1.x); a[5] = f2bf(f1.y); a[6] = f2bf(f1.z); a[7] = f2bf(f1.w);
        df[j] = a;
    }

    // ---- prologue 3: convert all sc fragments to bf16 (statically indexed) ----
    bf16x8 bb[TILES];
    #pragma unroll
    for (int tt = 0; tt < TILES; ++tt) {
        bf16x8 r;
        r[0] = f2bf(ra[tt].x); r[1] = f2bf(ra[tt].y);
        r[2] = f2bf(ra[tt].z); r[3] = f2bf(ra[tt].w);
        r[4] = f2bf(rb[tt].x); r[5] = f2bf(rb[tt].y);
        r[6] = f2bf(rb[tt].z); r[7] = f2bf(rb[tt].w);
        bb[tt] = r;
    }

    // MFMA pass for one tile -> staging buffer buf.
    auto compute = [&](const bf16x8& bbx, float* buf) {
        #pragma unroll
        for (int j = 0; j < 15; ++j) {
            const int ch = wid + 4 * j;
            if (ch < NCHT) {                         // wave-uniform
                f32x4 z = {0.f, 0.f, 0.f, 0.f};
                f32x4 acc = __builtin_amdgcn_mfma_f32_16x16x32_bf16(df[j], bbx, z, 0, 0, 0);
                if (ch != 56) {
                    *reinterpret_cast<f32x4*>(&buf[brow * DDIM + ch * 16 + dloc]) = acc;
                } else if (dloc == 0) {              // only d=896..899 valid
                    *reinterpret_cast<f32x4*>(&buf[brow * DDIM + 896]) = acc;
                }
            }
        }
    };

    compute(bb[0], stg[0]);
    barrier_lds();

    const int base = t * 4;

    // ---- steady loop: NO vmem reads, NO vmcnt waits. Fully unrolled so all
    // bb[] indexing is static (rule #20). ----
    #pragma unroll
    for (int tile = 0; tile < TILES; ++tile) {
        // compute tile+1 into the other buffer (MFMA + ds_write pipes)
        if (tile + 1 < TILES) compute(bb[tile + 1], stg[(tile + 1) & 1]);

        // copy tile from stg[tile&1]: literal fill pattern, contiguous
        float* __restrict__ tbase = out + (size_t)(b0 + (long long)tile * TROWS) * DDIM;
        const float* __restrict__ buf = stg[tile & 1];
        #pragma unroll
        for (int i = 0; i < 14; ++i) {
            const int o = i * 1024 + base;           // 14*1024 = 14336
            f32x4 v = *reinterpret_cast<const f32x4*>(&buf[o]);
            *reinterpret_cast<f32x4*>(tbase + o) = v;
        }
        if (t < 16) {                                // 14336 + 64 = 14400
            const int o = 14336 + base;
            f32x4 v = *reinterpret_cast<const f32x4*>(&buf[o]);
            *reinterpret_cast<f32x4*>(tbase + o) = v;
        }

        if (tile + 1 < TILES) barrier_lds();         // stores stay in flight
    }
}

extern "C" void kernel_launch(void* const* d_in, const int* in_sizes, int n_in,
                              void* d_out, int out_size, void* d_ws, size_t ws_size,
                              hipStream_t stream) {
    const float* sc   = (const float*)d_in[0];   // [B, 32]
    const float* dict = (const float*)d_in[1];   // [900, 32]
    float* out        = (float*)d_out;           // [B, 1, 30, 30] flat = [B, 900]

    const int B = in_sizes[0] / KD;              // 262144 (divisible by RPB=256)

    mfma_decode<<<dim3((unsigned)(B / RPB)), 256, 0, stream>>>(sc, dict, out, B);
}